// Round 1
// baseline (137.801 us; speedup 1.0000x reference)
//
#include <hip/hip_runtime.h>
#include <hip/hip_bf16.h>

#define DTILE 8
#define NDIR  6112   // 64 + 64*63 + 64*63/2

// ---------------------------------------------------------------------------
// prep: transposes (for coalesced reads in main), direction table, zero acc
// ---------------------------------------------------------------------------
__global__ void prep_kernel(const float* __restrict__ W1, const float* __restrict__ W2,
                            float* __restrict__ W1t, float* __restrict__ W2t,
                            int4* __restrict__ tab, double* __restrict__ acc) {
    int gtid = blockIdx.x * blockDim.x + threadIdx.x;
    int gsz  = gridDim.x * blockDim.x;
    // W1 is (256,64) row-major -> W1t[i][n] = W1[n][i]   (64 x 256)
    for (int idx = gtid; idx < 256 * 64; idx += gsz) {
        int n = idx >> 6, i = idx & 63;
        W1t[i * 256 + n] = W1[idx];
    }
    // W2 is (256,256) row-major -> W2t[n][m] = W2[m][n]
    for (int idx = gtid; idx < 256 * 256; idx += gsz) {
        int m = idx >> 8, n = idx & 255;
        W2t[n * 256 + m] = W2[idx];
    }
    // direction table: (i, j, p, q);  w = p*W1[:,i] + q*W1[:,j]
    for (int t = gtid; t < NDIR; t += gsz) {
        int i, j, p, q;
        if (t < 64) { i = t; j = t; p = 4; q = 0; }
        else if (t < 64 + 64 * 63) {
            int u = t - 64;
            i = u / 63;
            int jj = u % 63;
            j = jj + (jj >= i ? 1 : 0);
            p = 3; q = 1;
        } else {
            int u = t - (64 + 64 * 63);
            // pairs (i<j): base(i) = i*(127-i)/2
            int ii = 0;
            while ((ii + 1) * (127 - (ii + 1)) / 2 <= u) ii++;
            i = ii;
            j = i + 1 + (u - i * (127 - i) / 2);
            p = 2; q = 2;
        }
        tab[t] = make_int4(i, j, p, q);
    }
    if (gtid == 0) *acc = 0.0;
}

// ---------------------------------------------------------------------------
// coef: base-point tanh derivative constants for both layers (1 block, 256 thr)
//   layer1: c_k[n] = phi^(k)(u0[n]),   u0 = W1 x + b1
//   layer2: E_k[m] = W3[m] * phi^(k)(g0[m]),  g0 = W2 tanh(u0) + b2
// ---------------------------------------------------------------------------
__global__ __launch_bounds__(256) void coef_kernel(
        const float* __restrict__ x,  const float* __restrict__ W1, const float* __restrict__ b1,
        const float* __restrict__ W2, const float* __restrict__ b2, const float* __restrict__ W3,
        float* __restrict__ c, float* __restrict__ E) {
    __shared__ float xs[64];
    __shared__ float h0[256];
    int tid = threadIdx.x;
    if (tid < 64) xs[tid] = x[tid];
    __syncthreads();

    float u = b1[tid];
    const float* wr = W1 + tid * 64;
    #pragma unroll 8
    for (int i = 0; i < 64; i++) u += wr[i] * xs[i];
    float T = tanhf(u), s = 1.f - T * T;
    c[tid]       = s;                          // phi'
    c[256 + tid] = -2.f * T * s;               // phi''
    c[512 + tid] = s * (6.f * T * T - 2.f);    // phi'''
    c[768 + tid] = s * T * (16.f - 24.f * T * T); // phi''''
    h0[tid] = T;
    __syncthreads();

    float g = b2[tid];
    const float* w2r = W2 + tid * 256;
    #pragma unroll 4
    for (int n = 0; n < 256; n++) g += w2r[n] * h0[n];
    float T2 = tanhf(g), s2 = 1.f - T2 * T2;
    float w3 = W3[tid];
    E[tid]       = w3 * s2;
    E[256 + tid] = w3 * (-2.f * T2 * s2);
    E[512 + tid] = w3 * (s2 * (6.f * T2 * T2 - 2.f));
    E[768 + tid] = w3 * (s2 * T2 * (16.f - 24.f * T2 * T2));
}

// ---------------------------------------------------------------------------
// main: per direction, g_k = W2 @ (c_k * w^k), k=1..4; quartic combine; reduce
// One block = DTILE directions; thread m owns output row m.
// ---------------------------------------------------------------------------
__global__ __launch_bounds__(256) void main_kernel(
        const float* __restrict__ c, const float* __restrict__ E,
        const float* __restrict__ W1t, const float* __restrict__ W2t,
        const int4* __restrict__ tab, double* __restrict__ acc) {
    __shared__ float4 hls[DTILE * 256];     // 32 KB: (h1,h2,h3,h4) per (dir,n)
    __shared__ double wsum[4];
    int tid = threadIdx.x;
    int t0  = blockIdx.x * DTILE;

    // phase 1: build scaled-power vectors
    {
        int n = tid;
        float c1 = c[n], c2 = c[256 + n], c3 = c[512 + n], c4 = c[768 + n];
        #pragma unroll
        for (int d = 0; d < DTILE; d++) {
            int4 tt = tab[t0 + d];
            float w  = (float)tt.z * W1t[tt.x * 256 + n] + (float)tt.w * W1t[tt.y * 256 + n];
            float w2 = w * w;
            hls[d * 256 + n] = make_float4(c1 * w, c2 * w2, c3 * w2 * w, c4 * w2 * w2);
        }
    }
    __syncthreads();

    // phase 2: 4 matvecs per direction, all directions at once
    float g[DTILE][4];
    #pragma unroll
    for (int d = 0; d < DTILE; d++) { g[d][0] = 0.f; g[d][1] = 0.f; g[d][2] = 0.f; g[d][3] = 0.f; }
    int m = tid;
    #pragma unroll 4
    for (int n = 0; n < 256; n++) {
        float wv = W2t[n * 256 + m];           // coalesced across lanes
        #pragma unroll
        for (int d = 0; d < DTILE; d++) {
            float4 h = hls[d * 256 + n];       // broadcast (free)
            g[d][0] += wv * h.x;
            g[d][1] += wv * h.y;
            g[d][2] += wv * h.z;
            g[d][3] += wv * h.w;
        }
    }

    // combine: y4[m] = E4 g1^4 + 6 E3 g1^2 g2 + 3 E2 g2^2 + 4 E2 g1 g3 + E1 g4
    float E1 = E[m], E2 = E[256 + m], E3 = E[512 + m], E4 = E[768 + m];
    double part = 0.0;
    #pragma unroll
    for (int d = 0; d < DTILE; d++) {
        int t = t0 + d;
        float wgt = (t < 64) ? 0.359375f                 // alpha = 92/256
                  : (t < 64 + 64 * 63) ? (-1.f / 36.f)   // beta
                  : (5.f / 96.f);                        // gamma
        float g1 = g[d][0], g2 = g[d][1], g3 = g[d][2], g4 = g[d][3];
        float g1sq = g1 * g1;
        float y = E4 * g1sq * g1sq + 6.f * E3 * g1sq * g2 + 3.f * E2 * g2 * g2
                + 4.f * E2 * g1 * g3 + E1 * g4;
        part += (double)(wgt * y);
    }

    // block reduce (4 waves of 64) then one f64 atomic per block
    for (int off = 32; off > 0; off >>= 1) part += __shfl_down(part, off, 64);
    int wave = tid >> 6;
    if ((tid & 63) == 0) wsum[wave] = part;
    __syncthreads();
    if (tid == 0) atomicAdd(acc, wsum[0] + wsum[1] + wsum[2] + wsum[3]);
}

__global__ void finish_kernel(const double* __restrict__ acc, float* __restrict__ out) {
    out[0] = (float)(*acc);
}

// ---------------------------------------------------------------------------
extern "C" void kernel_launch(void* const* d_in, const int* in_sizes, int n_in,
                              void* d_out, int out_size, void* d_ws, size_t ws_size,
                              hipStream_t stream) {
    const float* x  = (const float*)d_in[0];
    const float* W1 = (const float*)d_in[1];
    const float* b1 = (const float*)d_in[2];
    const float* W2 = (const float*)d_in[3];
    const float* b2 = (const float*)d_in[4];
    const float* W3 = (const float*)d_in[5];
    // b3 (d_in[6]) does not affect the 4th derivative

    char* ws = (char*)d_ws;
    double* acc = (double*)ws;                               // 8 B
    float*  c   = (float*)(ws + 16);                         // 1024 f
    float*  E   = (float*)(ws + 16 + 4096);                  // 1024 f
    float*  W1t = (float*)(ws + 16 + 8192);                  // 16384 f
    float*  W2t = (float*)(ws + 16 + 8192 + 65536);          // 65536 f
    int4*   tab = (int4*)(ws + 16 + 8192 + 65536 + 262144);  // 6112 int4
    float*  out = (float*)d_out;

    prep_kernel<<<128, 256, 0, stream>>>(W1, W2, W1t, W2t, tab, acc);
    coef_kernel<<<1, 256, 0, stream>>>(x, W1, b1, W2, b2, W3, c, E);
    main_kernel<<<NDIR / DTILE, 256, 0, stream>>>(c, E, W1t, W2t, tab, acc);
    finish_kernel<<<1, 1, 0, stream>>>(acc, out);
}

// Round 4
// 109.254 us; speedup vs baseline: 1.2613x; 1.2613x over previous
//
#include <hip/hip_runtime.h>
#include <hip/hip_bf16.h>

// ---------------------------------------------------------------------------
// Closed-form bilaplacian of f(x) = W3 tanh(W2 tanh(W1 x + b1) + b2) + b3.
//
// Sum over all (i,j) of d^4 f / dx_i^2 dx_j^2 via Faa di Bruno:
//   c_k[n] = phi^(k)(u0)_n  (layer-1 tanh derivs at base point)
//   E_k[m] = W3_m * phi^(k)(v0)_m
//   A = W1 (256x64), a_i = A[:,i]
//   P[m][i] = [W2 (c1 * a_i)]_m              (256x64)
//   G[n][n'] = <A_n, A_n'> (row Gram)        (256x256)
//   T[m][n] = sum_i P[m][i] A[n][i]          (256x256, never stored)
//   r2[n] = |A_n|^2
// per-m: p2 = sum_i P^2, q = sum_n c2 W2 r2, s3 = sum_n c2 W2 T^2,
//        s4 = sum_n c3 r2 W2 T, s5 = sum_n c4 r2^2 W2, u = s^T G^2 s (s = c2*W2row)
// Delta^2 f = sum_m E4 p2^2 + E3 (2 q p2 + 4 s3) + E2 (q^2 + 2 u + 4 s4) + E1 s5
// ---------------------------------------------------------------------------

// ws float-index layout (floats start at byte 16; double acc @0, int counter @8)
#define C_F    0        // c[4][256]
#define H0_F   1024     // tanh(u0)
#define R2_F   1280     // row norms^2
#define E_F    1536     // E[4][256]
#define Q_F    2560
#define S5_F   2816
#define U_F    3072
#define W1T_F  3328     // [64][256]
#define G_F    19712    // [256][256]
#define P_F    85248    // [256][64]
// total floats = 101632 -> ~397 KB

// ---------------------------------------------------------------------------
// K1: block 0 = layer-1 coefs (+zero acc/counter); blocks 1..16 = Gram tiles;
//     blocks 17..20 = W1 transpose.
// ---------------------------------------------------------------------------
__global__ __launch_bounds__(256) void k1_kernel(
    const float* __restrict__ x, const float* __restrict__ W1,
    const float* __restrict__ b1, float* __restrict__ ws_f,
    double* __restrict__ acc, int* __restrict__ cnt) {
    __shared__ __align__(16) float smem[2 * 64 * 68];
    int tid = threadIdx.x, b = blockIdx.x;

    if (b == 0) {
        float* xs = smem;
        if (tid < 64) xs[tid] = x[tid];
        __syncthreads();
        const float4* row = (const float4*)(W1 + tid * 64);
        const float4* xv4 = (const float4*)xs;
        float u0 = b1[tid], r2v = 0.f;
        #pragma unroll
        for (int k = 0; k < 16; k++) {
            float4 w = row[k], xv = xv4[k];
            u0  += w.x * xv.x + w.y * xv.y + w.z * xv.z + w.w * xv.w;
            r2v += w.x * w.x + w.y * w.y + w.z * w.z + w.w * w.w;
        }
        float T = tanhf(u0), s = 1.f - T * T;
        ws_f[C_F + tid]       = s;
        ws_f[C_F + 256 + tid] = -2.f * T * s;
        ws_f[C_F + 512 + tid] = s * (6.f * T * T - 2.f);
        ws_f[C_F + 768 + tid] = s * T * (16.f - 24.f * T * T);
        ws_f[H0_F + tid] = T;
        ws_f[R2_F + tid] = r2v;
        if (tid == 0) { *acc = 0.0; *cnt = 0; }
    } else if (b <= 16) {
        int tb = b - 1, nb = tb >> 2, pb = tb & 3;
        float* As = smem;
        float* Bs = smem + 64 * 68;
        for (int idx = tid; idx < 4096; idx += 256) {
            int r = idx >> 6, i = idx & 63;
            As[i * 68 + r] = W1[(nb * 64 + r) * 64 + i];
            Bs[i * 68 + r] = W1[(pb * 64 + r) * 64 + i];
        }
        __syncthreads();
        int r0 = (tid & 15) * 4, c0 = (tid >> 4) * 4;
        float a[4][4] = {};
        for (int i = 0; i < 64; i++) {
            float4 av = *(const float4*)&As[i * 68 + r0];
            float4 bv = *(const float4*)&Bs[i * 68 + c0];
            float ar[4] = {av.x, av.y, av.z, av.w};
            float br[4] = {bv.x, bv.y, bv.z, bv.w};
            #pragma unroll
            for (int rr = 0; rr < 4; rr++)
                #pragma unroll
                for (int cc = 0; cc < 4; cc++)
                    a[rr][cc] = fmaf(ar[rr], br[cc], a[rr][cc]);
        }
        float* G = ws_f + G_F;
        #pragma unroll
        for (int rr = 0; rr < 4; rr++)
            #pragma unroll
            for (int cc = 0; cc < 4; cc++)
                G[(nb * 64 + r0 + rr) * 256 + pb * 64 + c0 + cc] = a[rr][cc];
    } else {
        int base = (b - 17) * 4096;
        float* W1t = ws_f + W1T_F;
        for (int idx = base + tid; idx < base + 4096; idx += 256) {
            int n = idx >> 6, i = idx & 63;
            W1t[i * 256 + n] = W1[idx];
        }
    }
}

// ---------------------------------------------------------------------------
// K2: blocks 0..7 = P tiles (32m x 64i); 8..11 = v0/E; 12..267 = u,q,s5 per m.
// ---------------------------------------------------------------------------
__global__ __launch_bounds__(256) void k2_kernel(
    const float* __restrict__ W1, const float* __restrict__ W2,
    const float* __restrict__ b2, const float* __restrict__ W3,
    float* __restrict__ ws_f) {
    __shared__ __align__(16) float smem[64 * 34 + 64 * 68];
    int tid = threadIdx.x, b = blockIdx.x;
    const float* c1g = ws_f + C_F;
    const float* c2g = ws_f + C_F + 256;
    const float* c4g = ws_f + C_F + 768;

    if (b < 8) {                      // ---- P = W2 diag(c1) W1, tile m0..m0+31
        int m0 = b * 32;
        float* Wc = smem;             // [64n][34] (padded, m-minor)
        float* Bc = smem + 64 * 34;   // [64n][68] (padded, i-minor)
        float acc2[2][4] = {};
        int tm2 = (tid & 15) * 2, ti = (tid >> 4) * 4;
        for (int nc = 0; nc < 4; nc++) {
            __syncthreads();
            for (int idx = tid; idx < 2048; idx += 256) {
                int mm = idx >> 6, nn = idx & 63;
                Wc[nn * 34 + mm] = W2[(m0 + mm) * 256 + nc * 64 + nn];
            }
            for (int idx = tid; idx < 4096; idx += 256) {
                int nn = idx >> 6, ii = idx & 63, n = nc * 64 + nn;
                Bc[nn * 68 + ii] = c1g[n] * W1[n * 64 + ii];
            }
            __syncthreads();
            for (int nn = 0; nn < 64; nn++) {
                float2 a2 = *(const float2*)&Wc[nn * 34 + tm2];
                float4 b4 = *(const float4*)&Bc[nn * 68 + ti];
                float br[4] = {b4.x, b4.y, b4.z, b4.w};
                #pragma unroll
                for (int j = 0; j < 4; j++) {
                    acc2[0][j] = fmaf(a2.x, br[j], acc2[0][j]);
                    acc2[1][j] = fmaf(a2.y, br[j], acc2[1][j]);
                }
            }
        }
        float* P = ws_f + P_F;
        #pragma unroll
        for (int j = 0; j < 4; j++) {
            P[(m0 + tm2) * 64 + ti + j]     = acc2[0][j];
            P[(m0 + tm2 + 1) * 64 + ti + j] = acc2[1][j];
        }
    } else if (b < 12) {              // ---- v0 = W2 h0 + b2 -> E1..E4
        int m0 = (b - 8) * 64;
        float* Ws  = smem;            // [64n][65] (m-minor)
        float* h0s = smem + 64 * 65;  // 256
        float* part = h0s + 256;      // 256
        h0s[tid] = ws_f[H0_F + tid];
        int mm = tid & 63, nq = tid >> 6;
        float partial = 0.f;
        for (int nc = 0; nc < 4; nc++) {
            __syncthreads();
            for (int idx = tid; idx < 4096; idx += 256) {
                int m2 = idx >> 6, nn = idx & 63;
                Ws[nn * 65 + m2] = W2[(m0 + m2) * 256 + nc * 64 + nn];
            }
            __syncthreads();
            #pragma unroll
            for (int k = 0; k < 16; k++) {
                int nn = nq * 16 + k;
                partial = fmaf(Ws[nn * 65 + mm], h0s[nc * 64 + nn], partial);
            }
        }
        part[nq * 64 + mm] = partial;
        __syncthreads();
        if (tid < 64) {
            int m = m0 + tid;
            float v = b2[m] + part[tid] + part[64 + tid] + part[128 + tid] + part[192 + tid];
            float T2 = tanhf(v), s2 = 1.f - T2 * T2, w3 = W3[m];
            float* E = ws_f + E_F;
            E[m]       = w3 * s2;
            E[256 + m] = -2.f * w3 * T2 * s2;
            E[512 + m] = w3 * s2 * (6.f * T2 * T2 - 2.f);
            E[768 + m] = w3 * s2 * T2 * (16.f - 24.f * T2 * T2);
        }
    } else {                          // ---- u_m = s^T G^2 s, plus q_m, s5_m
        int m = b - 12;
        float* cw  = smem;            // 256
        float* red = smem + 256;      // 12
        float w2r = W2[m * 256 + tid], c2r = c2g[tid];
        float cwv = c2r * w2r;
        cw[tid] = cwv;
        __syncthreads();
        const float* G = ws_f + G_F;
        float km = 0.f;
        #pragma unroll 4
        for (int np = 0; np < 256; np++) {
            float g = G[np * 256 + tid];       // coalesced row; symmetric G
            km = fmaf(g * g, cw[np], km);
        }
        float r2r = ws_f[R2_F + tid], c4r = c4g[tid];
        float uv  = km * cwv;
        float qv  = cwv * r2r;
        float s5v = w2r * c4r * r2r * r2r;
        for (int o = 32; o > 0; o >>= 1) {
            uv  += __shfl_down(uv, o, 64);
            qv  += __shfl_down(qv, o, 64);
            s5v += __shfl_down(s5v, o, 64);
        }
        int w = tid >> 6;
        if ((tid & 63) == 0) { red[w * 3] = uv; red[w * 3 + 1] = qv; red[w * 3 + 2] = s5v; }
        __syncthreads();
        if (tid == 0) {
            ws_f[U_F + m]  = red[0] + red[3] + red[6] + red[9];
            ws_f[Q_F + m]  = red[1] + red[4] + red[7] + red[10];
            ws_f[S5_F + m] = red[2] + red[5] + red[8] + red[11];
        }
    }
}

// ---------------------------------------------------------------------------
// K3: per m, T-row fused s3/s4/p2; combine; f64 atomic; last block finalizes.
// ---------------------------------------------------------------------------
__global__ __launch_bounds__(256) void k3_kernel(
    const float* __restrict__ W2, float* __restrict__ ws_f,
    double* __restrict__ acc, int* __restrict__ cnt, float* __restrict__ out) {
    __shared__ __align__(16) float smem[64 + 16];
    int tid = threadIdx.x, m = blockIdx.x;
    float* Ps  = smem;
    float* red = smem + 64;
    const float* P = ws_f + P_F;
    if (tid < 64) Ps[tid] = P[m * 64 + tid];
    __syncthreads();
    const float* W1t = ws_f + W1T_F;
    float T = 0.f;
    #pragma unroll 4
    for (int i = 0; i < 64; i++) T = fmaf(Ps[i], W1t[i * 256 + tid], T);
    float w2r = W2[m * 256 + tid];
    float c2r = ws_f[C_F + 256 + tid], c3r = ws_f[C_F + 512 + tid];
    float r2r = ws_f[R2_F + tid];
    float s3v = c2r * w2r * T * T;
    float s4v = c3r * r2r * w2r * T;
    float p2v = (tid < 64) ? Ps[tid] * Ps[tid] : 0.f;
    for (int o = 32; o > 0; o >>= 1) {
        s3v += __shfl_down(s3v, o, 64);
        s4v += __shfl_down(s4v, o, 64);
        p2v += __shfl_down(p2v, o, 64);
    }
    int w = tid >> 6;
    if ((tid & 63) == 0) { red[w * 3] = s3v; red[w * 3 + 1] = s4v; red[w * 3 + 2] = p2v; }
    __syncthreads();
    if (tid == 0) {
        float s3 = red[0] + red[3] + red[6] + red[9];
        float s4 = red[1] + red[4] + red[7] + red[10];
        float p2 = red[2] + red[5] + red[8] + red[11];
        const float* E = ws_f + E_F;
        float qm = ws_f[Q_F + m], um = ws_f[U_F + m], s5m = ws_f[S5_F + m];
        float y = E[768 + m] * p2 * p2
                + E[512 + m] * (2.f * qm * p2 + 4.f * s3)
                + E[256 + m] * (qm * qm + 2.f * um + 4.f * s4)
                + E[m] * s5m;
        atomicAdd(acc, (double)y);
        __threadfence();
        int t = atomicAdd(cnt, 1);
        if (t == 255) {
            __threadfence();
            out[0] = (float)atomicAdd(acc, 0.0);
        }
    }
}

// ---------------------------------------------------------------------------
extern "C" void kernel_launch(void* const* d_in, const int* in_sizes, int n_in,
                              void* d_out, int out_size, void* d_ws, size_t ws_size,
                              hipStream_t stream) {
    const float* x  = (const float*)d_in[0];
    const float* W1 = (const float*)d_in[1];
    const float* b1 = (const float*)d_in[2];
    const float* W2 = (const float*)d_in[3];
    const float* b2 = (const float*)d_in[4];
    const float* W3 = (const float*)d_in[5];
    // b3 does not affect the 4th derivative

    char* ws = (char*)d_ws;
    double* acc  = (double*)ws;
    int*    cnt  = (int*)(ws + 8);
    float*  ws_f = (float*)(ws + 16);
    float*  out  = (float*)d_out;

    k1_kernel<<<21, 256, 0, stream>>>(x, W1, b1, ws_f, acc, cnt);
    k2_kernel<<<268, 256, 0, stream>>>(W1, W2, b2, W3, ws_f);
    k3_kernel<<<256, 256, 0, stream>>>(W2, ws_f, acc, cnt, out);
}

// Round 5
// 104.568 us; speedup vs baseline: 1.3178x; 1.0448x over previous
//
#include <hip/hip_runtime.h>
#include <hip/hip_bf16.h>

// ---------------------------------------------------------------------------
// Closed-form bilaplacian of f(x) = W3 tanh(W2 tanh(W1 x + b1) + b2) + b3.
//   c_k[n] = phi^(k)(u0)_n ; E_k[m] = W3_m phi^(k)(v0)_m
//   A = W1 (256x64); P[m][i] = [W2 diag(c1) W1]_{m,i}; G = A A^T (row Gram)
//   T[m][n] = sum_i P[m][i] A[n][i]; r2[n] = |A_n|^2
// per-m: p2 = sum_i P^2; q = W2 (c2*r2); s5 = W2 (c4*r2^2)
//        s3 = sum_n c2 W2[m][n] T[m][n]^2 ; s4 = sum_n c3 r2 W2[m][n] T[m][n]
//        u  = s^T (G.*G) s  with s = c2 * W2row_m   (elementwise square!)
// Delta^2 f = sum_m E4 p2^2 + E3(2 q p2 + 4 s3) + E2(q^2 + 2u + 4 s4) + E1 s5
//
// All heavy phases are 64x64-tile LDS GEMMs with 4x4 register blocking
// (k1-Gram pattern): latency-tolerant, not per-m serial load chains.
// ---------------------------------------------------------------------------

// ws float offsets (floats start at byte 16; int cnt at byte 0)
#define C_F    0        // c1..c4 [4][256]
#define H0_F   1024
#define R2_F   1280
#define E_F    1536     // E1..E4 [4][256]
#define Q_F    2560
#define S5_F   2816
#define U_F    3072
#define S3_F   3328
#define S4_F   3584
#define P2_F   3840
#define G_F    4096     // [256][256]
#define P_F    69632    // [256][64]
// total 86016 floats = 344 KB

// ---------------------------------------------------------------------------
// K1: block 0 = coefs + zero u/s3/s4/cnt; blocks 1..16 = Gram tiles.
// ---------------------------------------------------------------------------
__global__ __launch_bounds__(256) void k1_kernel(
    const float* __restrict__ x, const float* __restrict__ W1,
    const float* __restrict__ b1, float* __restrict__ ws_f, int* __restrict__ cnt) {
    __shared__ __align__(16) float smem[2 * 64 * 68];
    int tid = threadIdx.x, b = blockIdx.x;

    if (b == 0) {
        float* xs = smem;
        if (tid < 64) xs[tid] = x[tid];
        __syncthreads();
        const float4* row = (const float4*)(W1 + tid * 64);
        const float4* xv4 = (const float4*)xs;
        float u0 = b1[tid], r2v = 0.f;
        #pragma unroll
        for (int k = 0; k < 16; k++) {
            float4 w = row[k], xv = xv4[k];
            u0  += w.x * xv.x + w.y * xv.y + w.z * xv.z + w.w * xv.w;
            r2v += w.x * w.x + w.y * w.y + w.z * w.z + w.w * w.w;
        }
        float T = tanhf(u0), s = 1.f - T * T;
        ws_f[C_F + tid]       = s;
        ws_f[C_F + 256 + tid] = -2.f * T * s;
        ws_f[C_F + 512 + tid] = s * (6.f * T * T - 2.f);
        ws_f[C_F + 768 + tid] = s * T * (16.f - 24.f * T * T);
        ws_f[H0_F + tid] = T;
        ws_f[R2_F + tid] = r2v;
        ws_f[U_F  + tid] = 0.f;
        ws_f[S3_F + tid] = 0.f;
        ws_f[S4_F + tid] = 0.f;
        if (tid == 0) *cnt = 0;
    } else {
        int tb = b - 1, nb = tb >> 2, pb = tb & 3;
        float* As = smem;
        float* Bs = smem + 64 * 68;
        for (int idx = tid; idx < 4096; idx += 256) {
            int r = idx >> 6, i = idx & 63;
            As[i * 68 + r] = W1[(nb * 64 + r) * 64 + i];
            Bs[i * 68 + r] = W1[(pb * 64 + r) * 64 + i];
        }
        __syncthreads();
        int r0 = (tid & 15) * 4, c0 = (tid >> 4) * 4;
        float a[4][4] = {};
        for (int i = 0; i < 64; i++) {
            float4 av = *(const float4*)&As[i * 68 + r0];
            float4 bv = *(const float4*)&Bs[i * 68 + c0];
            float ar[4] = {av.x, av.y, av.z, av.w};
            float br[4] = {bv.x, bv.y, bv.z, bv.w};
            #pragma unroll
            for (int rr = 0; rr < 4; rr++)
                #pragma unroll
                for (int cc = 0; cc < 4; cc++)
                    a[rr][cc] = fmaf(ar[rr], br[cc], a[rr][cc]);
        }
        float* G = ws_f + G_F;
        #pragma unroll
        for (int rr = 0; rr < 4; rr++)
            #pragma unroll
            for (int cc = 0; cc < 4; cc++)
                G[(nb * 64 + r0 + rr) * 256 + pb * 64 + c0 + cc] = a[rr][cc];
    }
}

// ---------------------------------------------------------------------------
// K2: b 0..7 = P tiles (+p2); b 8..11 = E/q/s5 (one W2 pass, 3 matvecs);
//     b 12..27 = u-GEMM: Yt = (G.*G*diag(c2)) @ W2^T, u = <S, Yt> per column.
// ---------------------------------------------------------------------------
__global__ __launch_bounds__(256) void k2_kernel(
    const float* __restrict__ W1, const float* __restrict__ W2,
    const float* __restrict__ b2, const float* __restrict__ W3,
    float* __restrict__ ws_f) {
    __shared__ __align__(16) float smem[13248];
    int tid = threadIdx.x, b = blockIdx.x;
    const float* c1g = ws_f + C_F;
    const float* c2g = ws_f + C_F + 256;
    const float* c4g = ws_f + C_F + 768;

    if (b < 8) {                      // ---- P = W2 diag(c1) W1 (+ p2 per m)
        int m0 = b * 32;
        float* Wc = smem;             // [64n][34]
        float* Bc = smem + 64 * 34;   // [64n][68]
        float acc2[2][4] = {};
        int tm2 = (tid & 15) * 2, ti = (tid >> 4) * 4;
        for (int nc = 0; nc < 4; nc++) {
            __syncthreads();
            for (int idx = tid; idx < 2048; idx += 256) {
                int mm = idx >> 6, nn = idx & 63;
                Wc[nn * 34 + mm] = W2[(m0 + mm) * 256 + nc * 64 + nn];
            }
            for (int idx = tid; idx < 4096; idx += 256) {
                int nn = idx >> 6, ii = idx & 63, n = nc * 64 + nn;
                Bc[nn * 68 + ii] = c1g[n] * W1[n * 64 + ii];
            }
            __syncthreads();
            for (int nn = 0; nn < 64; nn++) {
                float2 a2 = *(const float2*)&Wc[nn * 34 + tm2];
                float4 b4 = *(const float4*)&Bc[nn * 68 + ti];
                float br[4] = {b4.x, b4.y, b4.z, b4.w};
                #pragma unroll
                for (int j = 0; j < 4; j++) {
                    acc2[0][j] = fmaf(a2.x, br[j], acc2[0][j]);
                    acc2[1][j] = fmaf(a2.y, br[j], acc2[1][j]);
                }
            }
        }
        float* P = ws_f + P_F;
        float s0 = 0.f, s1 = 0.f;
        #pragma unroll
        for (int j = 0; j < 4; j++) {
            P[(m0 + tm2) * 64 + ti + j]     = acc2[0][j];
            P[(m0 + tm2 + 1) * 64 + ti + j] = acc2[1][j];
            s0 += acc2[0][j] * acc2[0][j];
            s1 += acc2[1][j] * acc2[1][j];
        }
        __syncthreads();
        float* red = smem;            // [32][16]
        red[tm2 * 16 + (tid >> 4)]       = s0;
        red[(tm2 + 1) * 16 + (tid >> 4)] = s1;
        __syncthreads();
        if (tid < 32) {
            float p = 0.f;
            #pragma unroll
            for (int g = 0; g < 16; g++) p += red[tid * 16 + g];
            ws_f[P2_F + m0 + tid] = p;
        }
    } else if (b < 12) {              // ---- E, q, s5: one pass over W2 rows
        int m0 = (b - 8) * 64;
        float* Ws   = smem;           // [64n][65]
        float* h0s  = smem + 4160;
        float* aqs  = h0s + 256;
        float* a5s  = aqs + 256;
        float* part = a5s + 256;      // [3][256]
        float r2v = ws_f[R2_F + tid];
        h0s[tid] = ws_f[H0_F + tid];
        aqs[tid] = c2g[tid] * r2v;
        a5s[tid] = c4g[tid] * r2v * r2v;
        int mm = tid & 63, nq = tid >> 6;
        float pv = 0.f, pq = 0.f, p5 = 0.f;
        for (int nc = 0; nc < 4; nc++) {
            __syncthreads();
            for (int idx = tid; idx < 4096; idx += 256) {
                int m2 = idx >> 6, nn = idx & 63;
                Ws[nn * 65 + m2] = W2[(m0 + m2) * 256 + nc * 64 + nn];
            }
            __syncthreads();
            #pragma unroll
            for (int k = 0; k < 16; k++) {
                int nn = nq * 16 + k, n = nc * 64 + nn;
                float wv = Ws[nn * 65 + mm];
                pv = fmaf(wv, h0s[n], pv);
                pq = fmaf(wv, aqs[n], pq);
                p5 = fmaf(wv, a5s[n], p5);
            }
        }
        part[nq * 64 + mm]       = pv;
        part[256 + nq * 64 + mm] = pq;
        part[512 + nq * 64 + mm] = p5;
        __syncthreads();
        if (tid < 64) {
            int m = m0 + tid;
            float v  = b2[m] + part[tid] + part[64 + tid] + part[128 + tid] + part[192 + tid];
            float q  = part[256 + tid] + part[320 + tid] + part[384 + tid] + part[448 + tid];
            float s5 = part[512 + tid] + part[576 + tid] + part[640 + tid] + part[704 + tid];
            float T2 = tanhf(v), s2 = 1.f - T2 * T2, w3 = W3[m];
            float* E = ws_f + E_F;
            E[m]       = w3 * s2;
            E[256 + m] = -2.f * w3 * T2 * s2;
            E[512 + m] = w3 * s2 * (6.f * T2 * T2 - 2.f);
            E[768 + m] = w3 * s2 * T2 * (16.f - 24.f * T2 * T2);
            ws_f[Q_F + m]  = q;
            ws_f[S5_F + m] = s5;
        }
    } else {                          // ---- u-GEMM tile (kb,mb), K=256 over n
        int tb = b - 12, kb = tb >> 2, mb = tb & 3;
        float* As  = smem;            // [nn][68] k-minor: c2[n]*G[k][n]^2
        float* Bs  = smem + 4352;     // [nn][68] m-minor: W2[m][n]
        float* W2k = smem + 8704;     // [mm][68]: W2[m][k-range]
        float* c2k = smem + 13056;    // 64
        for (int idx = tid; idx < 4096; idx += 256) {
            int a_ = idx >> 6, b_ = idx & 63;
            W2k[a_ * 68 + b_] = W2[(mb * 64 + a_) * 256 + kb * 64 + b_];
        }
        if (tid < 64) c2k[tid] = c2g[kb * 64 + tid];
        int r0 = (tid & 15) * 4, c0 = (tid >> 4) * 4;
        float a[4][4] = {};
        const float* G = ws_f + G_F;
        for (int nc = 0; nc < 4; nc++) {
            __syncthreads();
            float c2v = c2g[nc * 64 + (tid & 63)];
            for (int idx = tid; idx < 4096; idx += 256) {
                int a_ = idx >> 6, b_ = idx & 63;
                float gv = G[(kb * 64 + a_) * 256 + nc * 64 + b_];
                As[b_ * 68 + a_] = c2v * gv * gv;
                Bs[b_ * 68 + a_] = W2[(mb * 64 + a_) * 256 + nc * 64 + b_];
            }
            __syncthreads();
            for (int nn = 0; nn < 64; nn++) {
                float4 av = *(const float4*)&As[nn * 68 + r0];
                float4 bv = *(const float4*)&Bs[nn * 68 + c0];
                float ar[4] = {av.x, av.y, av.z, av.w};
                float br[4] = {bv.x, bv.y, bv.z, bv.w};
                #pragma unroll
                for (int rr = 0; rr < 4; rr++)
                    #pragma unroll
                    for (int cc = 0; cc < 4; cc++)
                        a[rr][cc] = fmaf(ar[rr], br[cc], a[rr][cc]);
            }
        }
        // u_m += sum_k s_m[k] * Yt[k][m], s_m[k] = c2[k] W2[m][k]
        #pragma unroll
        for (int cc = 0; cc < 4; cc++) {
            float up = 0.f;
            #pragma unroll
            for (int rr = 0; rr < 4; rr++)
                up += a[rr][cc] * c2k[r0 + rr] * W2k[(c0 + cc) * 68 + r0 + rr];
            up += __shfl_xor(up, 8, 16);
            up += __shfl_xor(up, 4, 16);
            up += __shfl_xor(up, 2, 16);
            up += __shfl_xor(up, 1, 16);
            if ((tid & 15) == 0)
                atomicAdd(&ws_f[U_F + mb * 64 + c0 + cc], up);
        }
    }
}

// ---------------------------------------------------------------------------
// K3: 16 T-tile blocks (s3,s4 via shuffle+atomics); ticket; last block combines.
// ---------------------------------------------------------------------------
__global__ __launch_bounds__(256) void k3_kernel(
    const float* __restrict__ W1, const float* __restrict__ W2,
    float* __restrict__ ws_f, int* __restrict__ cnt, float* __restrict__ out) {
    __shared__ __align__(16) float smem[13248];
    __shared__ int isLast;
    __shared__ double dsum[4];
    int tid = threadIdx.x, b = blockIdx.x;
    int mb = b >> 2, nb = b & 3;
    float* As  = smem;            // P tile:  As[ii][68] m-minor
    float* Bs  = smem + 4352;     // W1 tile: Bs[ii][68] n-minor
    float* W2s = smem + 8704;     // [mm][68]
    float* c2s = smem + 13056;    // 64
    float* c34 = smem + 13120;    // 64: c3*r2
    const float* P = ws_f + P_F;
    for (int idx = tid; idx < 4096; idx += 256) {
        int a_ = idx >> 6, b_ = idx & 63;
        As[b_ * 68 + a_]  = P[(mb * 64 + a_) * 64 + b_];
        Bs[b_ * 68 + a_]  = W1[(nb * 64 + a_) * 64 + b_];
        W2s[a_ * 68 + b_] = W2[(mb * 64 + a_) * 256 + nb * 64 + b_];
    }
    if (tid < 64) {
        int n = nb * 64 + tid;
        c2s[tid] = ws_f[C_F + 256 + n];
        c34[tid] = ws_f[C_F + 512 + n] * ws_f[R2_F + n];
    }
    __syncthreads();
    int m0t = (tid >> 4) * 4, n0t = (tid & 15) * 4;
    float a[4][4] = {};
    for (int ii = 0; ii < 64; ii++) {
        float4 av = *(const float4*)&As[ii * 68 + m0t];
        float4 bv = *(const float4*)&Bs[ii * 68 + n0t];
        float ar[4] = {av.x, av.y, av.z, av.w};
        float br[4] = {bv.x, bv.y, bv.z, bv.w};
        #pragma unroll
        for (int rr = 0; rr < 4; rr++)
            #pragma unroll
            for (int cc = 0; cc < 4; cc++)
                a[rr][cc] = fmaf(ar[rr], br[cc], a[rr][cc]);
    }
    #pragma unroll
    for (int rr = 0; rr < 4; rr++) {
        float s3p = 0.f, s4p = 0.f;
        #pragma unroll
        for (int cc = 0; cc < 4; cc++) {
            float wv = W2s[(m0t + rr) * 68 + n0t + cc];
            float t  = a[rr][cc];
            s3p = fmaf(c2s[n0t + cc] * wv, t * t, s3p);
            s4p = fmaf(c34[n0t + cc] * wv, t, s4p);
        }
        s3p += __shfl_xor(s3p, 8, 16); s4p += __shfl_xor(s4p, 8, 16);
        s3p += __shfl_xor(s3p, 4, 16); s4p += __shfl_xor(s4p, 4, 16);
        s3p += __shfl_xor(s3p, 2, 16); s4p += __shfl_xor(s4p, 2, 16);
        s3p += __shfl_xor(s3p, 1, 16); s4p += __shfl_xor(s4p, 1, 16);
        if ((tid & 15) == 0) {
            atomicAdd(&ws_f[S3_F + mb * 64 + m0t + rr], s3p);
            atomicAdd(&ws_f[S4_F + mb * 64 + m0t + rr], s4p);
        }
    }
    __threadfence();
    if (tid == 0) isLast = (atomicAdd(cnt, 1) == 15) ? 1 : 0;
    __syncthreads();
    if (isLast) {
        int m = tid;
        float s3m = atomicAdd(&ws_f[S3_F + m], 0.f);
        float s4m = atomicAdd(&ws_f[S4_F + m], 0.f);
        float p2 = ws_f[P2_F + m], q = ws_f[Q_F + m];
        float um = ws_f[U_F + m],  s5 = ws_f[S5_F + m];
        const float* E = ws_f + E_F;
        float y = E[768 + m] * p2 * p2
                + E[512 + m] * (2.f * q * p2 + 4.f * s3m)
                + E[256 + m] * (q * q + 2.f * um + 4.f * s4m)
                + E[m] * s5;
        double part = (double)y;
        for (int off = 32; off > 0; off >>= 1) part += __shfl_down(part, off, 64);
        if ((tid & 63) == 0) dsum[tid >> 6] = part;
        __syncthreads();
        if (tid == 0) out[0] = (float)(dsum[0] + dsum[1] + dsum[2] + dsum[3]);
    }
}

// ---------------------------------------------------------------------------
extern "C" void kernel_launch(void* const* d_in, const int* in_sizes, int n_in,
                              void* d_out, int out_size, void* d_ws, size_t ws_size,
                              hipStream_t stream) {
    const float* x  = (const float*)d_in[0];
    const float* W1 = (const float*)d_in[1];
    const float* b1 = (const float*)d_in[2];
    const float* W2 = (const float*)d_in[3];
    const float* b2 = (const float*)d_in[4];
    const float* W3 = (const float*)d_in[5];
    // b3 does not affect the 4th derivative

    char* ws = (char*)d_ws;
    int*    cnt  = (int*)ws;
    float*  ws_f = (float*)(ws + 16);
    float*  out  = (float*)d_out;

    k1_kernel<<<17, 256, 0, stream>>>(x, W1, b1, ws_f, cnt);
    k2_kernel<<<28, 256, 0, stream>>>(W1, W2, b2, W3, ws_f);
    k3_kernel<<<16, 256, 0, stream>>>(W1, W2, ws_f, cnt, out);
}